// Round 2
// baseline (494.066 us; speedup 1.0000x reference)
//
#include <hip/hip_runtime.h>

#define DN 1024
#define SN 2048
#define BATCH 4
#define HN 16
#define HDN 64

typedef __attribute__((ext_vector_type(8))) short bf16x8;
typedef __attribute__((ext_vector_type(4))) float f32x4;

static __device__ __forceinline__ unsigned short f2b(float f) {
  unsigned u = __float_as_uint(f);
  unsigned r = (u + 0x7fffu + ((u >> 16) & 1u)) >> 16;
  return (unsigned short)r;
}

static __device__ __forceinline__ void gload16(const void* g, const void* l) {
  __builtin_amdgcn_global_load_lds(
      (const __attribute__((address_space(1))) unsigned int*)g,
      (__attribute__((address_space(3))) unsigned int*)l, 16, 0, 0);
}

// ---------------- weight transpose + bf16 convert: Wt[z][n][k] = bf16(W_z[k][n])
__global__ void wtrans(const float* __restrict__ W0, const float* __restrict__ W1,
                       const float* __restrict__ W2, const float* __restrict__ W3,
                       unsigned short* __restrict__ Wt) {
  __shared__ float tile[32][33];
  const int z = blockIdx.z;
  const float* W = (z == 0) ? W0 : (z == 1) ? W1 : (z == 2) ? W2 : W3;
  const int tx = threadIdx.x, ty = threadIdx.y;
  const int n0 = blockIdx.x * 32, k0 = blockIdx.y * 32;
#pragma unroll
  for (int j = ty; j < 32; j += 8)
    tile[j][tx] = W[(long)(k0 + j) * DN + n0 + tx];
  __syncthreads();
  unsigned short* o = Wt + (long)z * DN * DN;
#pragma unroll
  for (int j = ty; j < 32; j += 8)
    o[(long)(n0 + j) * DN + k0 + tx] = f2b(tile[tx][j]);
}

// ---------------- fp32 -> bf16 convert (8192*1024 elems)
__global__ void cvtbf16(const float* __restrict__ x, unsigned short* __restrict__ y) {
  const float4* xv = (const float4*)x;
  ushort4* yv = (ushort4*)y;
  for (int i = blockIdx.x * 256 + threadIdx.x; i < (8192 * 1024 / 4); i += 2048 * 256) {
    float4 vv = xv[i];
    ushort4 o;
    o.x = f2b(vv.x); o.y = f2b(vv.y); o.z = f2b(vv.z); o.w = f2b(vv.w);
    yv[i] = o;
  }
}

// ---------------- bf16 GEMM: C = A[M,K] * Bt[N,K]^T + bias, 128x128 tile, BK=32
// OUTMODE: 0 = bf16 row-major [M][N]; 1 = fp32 row-major [M][N]; 2 = bf16 [B][N][S] (V^T)
template <int OUTMODE>
__global__ __launch_bounds__(256, 2) void gemm128(
    const unsigned short* __restrict__ A, const unsigned short* __restrict__ Bt,
    const float* __restrict__ bias, void* __restrict__ Cout, int M, int N, int K) {
  __shared__ unsigned short Asm[128 * 32];
  __shared__ unsigned short Bsm[128 * 32];
  const int t = threadIdx.x;
  const int lane = t & 63, w = t >> 6;
  const int rl = lane & 15, g = lane >> 4;
  const int wm = (w >> 1) << 6, wn = (w & 1) << 6;
  const long bm = (long)blockIdx.x * 128, bn = (long)blockIdx.y * 128;

  f32x4 acc[4][4] = {};

  const int c0 = t, c1 = 256 + t;
  const int r0 = c0 >> 2, s0 = c0 & 3;
  const int r1 = c1 >> 2, s1 = c1 & 3;

  for (int k0 = 0; k0 < K; k0 += 32) {
    __syncthreads();
    gload16(A + (bm + r0) * K + k0 + s0 * 8, Asm + (w << 6) * 8);
    gload16(A + (bm + r1) * K + k0 + s1 * 8, Asm + (256 + (w << 6)) * 8);
    gload16(Bt + (bn + r0) * K + k0 + s0 * 8, Bsm + (w << 6) * 8);
    gload16(Bt + (bn + r1) * K + k0 + s1 * 8, Bsm + (256 + (w << 6)) * 8);
    asm volatile("s_waitcnt vmcnt(0)" ::: "memory");
    __syncthreads();
    bf16x8 af[4], bfr[4];
#pragma unroll
    for (int mf = 0; mf < 4; ++mf)
      af[mf] = *(const bf16x8*)(Asm + (wm + mf * 16 + rl) * 32 + g * 8);
#pragma unroll
    for (int nf = 0; nf < 4; ++nf)
      bfr[nf] = *(const bf16x8*)(Bsm + (wn + nf * 16 + rl) * 32 + g * 8);
#pragma unroll
    for (int mf = 0; mf < 4; ++mf)
#pragma unroll
      for (int nf = 0; nf < 4; ++nf)
        acc[mf][nf] = __builtin_amdgcn_mfma_f32_16x16x32_bf16(af[mf], bfr[nf], acc[mf][nf], 0, 0, 0);
  }

#pragma unroll
  for (int mf = 0; mf < 4; ++mf)
#pragma unroll
    for (int nf = 0; nf < 4; ++nf) {
      long col = bn + wn + nf * 16 + rl;
      float bv = bias[col];
      if (OUTMODE == 2) {
        long row0 = bm + wm + mf * 16 + g * 4;
        long bb = row0 >> 11, ss = row0 & 2047;
        ushort4 pack;
        pack.x = f2b(acc[mf][nf][0] + bv);
        pack.y = f2b(acc[mf][nf][1] + bv);
        pack.z = f2b(acc[mf][nf][2] + bv);
        pack.w = f2b(acc[mf][nf][3] + bv);
        *(ushort4*)((unsigned short*)Cout + (bb * DN + col) * SN + ss) = pack;
      } else {
#pragma unroll
        for (int r = 0; r < 4; ++r) {
          long row = bm + wm + mf * 16 + g * 4 + r;
          float vv = acc[mf][nf][r] + bv;
          if (OUTMODE == 1)
            ((float*)Cout)[row * N + col] = vv;
          else
            ((unsigned short*)Cout)[row * N + col] = f2b(vv);
        }
      }
    }
}

// ---------------- flash attention: grid (S/128, H, B), 256 thr = 4 waves x 32 q-rows
// Qh/Kh: [B][S][D] bf16; Vt: [B][D][S] bf16 (V transposed); AO: [B][S][D] bf16
__global__ __launch_bounds__(256, 2) void attnk(
    const unsigned short* __restrict__ Qh, const unsigned short* __restrict__ Kh,
    const unsigned short* __restrict__ Vt, const float* __restrict__ mask,
    unsigned short* __restrict__ AO) {
  const int t = threadIdx.x, lane = t & 63, w = t >> 6;
  const int rl = lane & 15, g = lane >> 4;
  const int qb = blockIdx.x * 128;
  const int h = blockIdx.y, b = blockIdx.z;

  __shared__ unsigned short KVs[8192];    // K [64][64] swz @0; V^T [64][64] swz @4096
  __shared__ unsigned short Ps[4][2048];  // per-wave P [32][64] swz
  __shared__ float ms[SN];

  const unsigned short* Qp = Qh + ((long)b * SN + qb) * DN + h * HDN;
  const unsigned short* Kp = Kh + (long)b * SN * DN + h * HDN;
  const unsigned short* Vp = Vt + ((long)b * DN + h * HDN) * SN;

  {  // mask -> LDS
    const float4* mp = (const float4*)(mask + (long)b * SN);
    float4* md = (float4*)ms;
    md[t] = mp[t];
    md[256 + t] = mp[256 + t];
  }

  // Q tile (128x64) into KVs region, swizzled source (chunk ^= r&7)
#pragma unroll
  for (int i = 0; i < 4; ++i) {
    int c = i * 256 + t;
    int r = c >> 3, sl = c & 7;
    gload16(Qp + (long)r * DN + ((sl ^ (r & 7)) << 3), KVs + ((i * 256 + (w << 6)) << 3));
  }
  asm volatile("s_waitcnt vmcnt(0)" ::: "memory");
  __syncthreads();

  bf16x8 qa[2][2];
#pragma unroll
  for (int mf = 0; mf < 2; ++mf) {
    int qr = (w << 5) + mf * 16 + rl;
#pragma unroll
    for (int ks = 0; ks < 2; ++ks) {
      int c16 = (ks * 4 + g) ^ (qr & 7);
      qa[mf][ks] = *(const bf16x8*)(KVs + qr * 64 + c16 * 8);
    }
  }

  f32x4 O[2][4] = {};
  float mstate[2][4], lstate[2][4];
#pragma unroll
  for (int mf = 0; mf < 2; ++mf)
#pragma unroll
    for (int r = 0; r < 4; ++r) { mstate[mf][r] = -1e30f; lstate[mf][r] = 0.f; }

  unsigned short* Pw = Ps[w];

  for (int t0 = 0; t0 < SN; t0 += 64) {
    __syncthreads();  // prior tile's LDS reads done before overwrite
    // stage K[64][64] swizzled (rows = kv, cols = d)
#pragma unroll
    for (int i = 0; i < 2; ++i) {
      int c = i * 256 + t;
      int r = c >> 3, sl = c & 7;
      gload16(Kp + (long)(t0 + r) * DN + ((sl ^ (r & 7)) << 3), KVs + ((i * 256 + (w << 6)) << 3));
    }
    // stage V^T [64][64] swizzled (rows = d, cols = kv; contiguous in s)
#pragma unroll
    for (int i = 0; i < 2; ++i) {
      int c = i * 256 + t;
      int r = c >> 3, sl = c & 7;
      gload16(Vp + (long)r * SN + t0 + ((sl ^ (r & 7)) << 3),
              KVs + 4096 + ((i * 256 + (w << 6)) << 3));
    }
    asm volatile("s_waitcnt vmcnt(0)" ::: "memory");
    __syncthreads();

    // QK^T
    f32x4 s[2][4] = {};
#pragma unroll
    for (int ks = 0; ks < 2; ++ks) {
      bf16x8 kb[4];
#pragma unroll
      for (int nf = 0; nf < 4; ++nf) {
        int kr = nf * 16 + rl;
        int c16 = (ks * 4 + g) ^ (kr & 7);
        kb[nf] = *(const bf16x8*)(KVs + kr * 64 + c16 * 8);
      }
#pragma unroll
      for (int mf = 0; mf < 2; ++mf)
#pragma unroll
        for (int nf = 0; nf < 4; ++nf)
          s[mf][nf] = __builtin_amdgcn_mfma_f32_16x16x32_bf16(qa[mf][ks], kb[nf], s[mf][nf], 0, 0, 0);
    }

    // scale + mask
    float sc[2][4][4];
    float mv[4];
#pragma unroll
    for (int nf = 0; nf < 4; ++nf) mv[nf] = ms[t0 + nf * 16 + rl] * -1e9f;
#pragma unroll
    for (int mf = 0; mf < 2; ++mf)
#pragma unroll
      for (int nf = 0; nf < 4; ++nf)
#pragma unroll
        for (int r = 0; r < 4; ++r)
          sc[mf][nf][r] = s[mf][nf][r] * 0.015625f + mv[nf];

    // online softmax (row owned per (g,r); reduce across the 16-lane group)
#pragma unroll
    for (int mf = 0; mf < 2; ++mf)
#pragma unroll
      for (int r = 0; r < 4; ++r) {
        float pm = fmaxf(fmaxf(sc[mf][0][r], sc[mf][1][r]), fmaxf(sc[mf][2][r], sc[mf][3][r]));
        pm = fmaxf(pm, __shfl_xor(pm, 1));
        pm = fmaxf(pm, __shfl_xor(pm, 2));
        pm = fmaxf(pm, __shfl_xor(pm, 4));
        pm = fmaxf(pm, __shfl_xor(pm, 8));
        float mo = mstate[mf][r];
        float mn = fmaxf(mo, pm);
        mstate[mf][r] = mn;
        float co = __expf(mo - mn);
        float rs = 0.f;
#pragma unroll
        for (int nf = 0; nf < 4; ++nf) {
          float p = __expf(sc[mf][nf][r] - mn);
          sc[mf][nf][r] = p;
          rs += p;
        }
        rs += __shfl_xor(rs, 1);
        rs += __shfl_xor(rs, 2);
        rs += __shfl_xor(rs, 4);
        rs += __shfl_xor(rs, 8);
        lstate[mf][r] = lstate[mf][r] * co + rs;
#pragma unroll
        for (int nf = 0; nf < 4; ++nf) O[mf][nf][r] *= co;
      }

    // write P (per-wave, swizzled [32][64])
#pragma unroll
    for (int mf = 0; mf < 2; ++mf)
#pragma unroll
      for (int nf = 0; nf < 4; ++nf) {
        int kv = nf * 16 + rl;
#pragma unroll
        for (int r = 0; r < 4; ++r) {
          int qq = mf * 16 + (g << 2) + r;
          int esw = qq * 64 + ((((kv >> 3) ^ (qq & 7))) << 3) + (kv & 7);
          Pw[esw] = f2b(sc[mf][nf][r]);
        }
      }

    // PV: P as A (read back swizzled), V^T rows as B (swizzled b128, same as K)
    bf16x8 pa[2][2];
#pragma unroll
    for (int mf = 0; mf < 2; ++mf)
#pragma unroll
      for (int ks = 0; ks < 2; ++ks) {
        int qq = mf * 16 + rl;
        int kb2 = ks * 4 + g;
        pa[mf][ks] = *(const bf16x8*)(Pw + qq * 64 + ((kb2 ^ (qq & 7)) << 3));
      }
#pragma unroll
    for (int ks = 0; ks < 2; ++ks)
#pragma unroll
      for (int nf = 0; nf < 4; ++nf) {
        int dr = nf * 16 + rl;  // d row of V^T
        int c16 = (ks * 4 + g) ^ (dr & 7);
        bf16x8 vb = *(const bf16x8*)(KVs + 4096 + dr * 64 + c16 * 8);
#pragma unroll
        for (int mf = 0; mf < 2; ++mf)
          O[mf][nf] = __builtin_amdgcn_mfma_f32_16x16x32_bf16(pa[mf][ks], vb, O[mf][nf], 0, 0, 0);
      }
  }

  // epilogue: O /= l, store bf16 to AO[b][q][h*64+d]
#pragma unroll
  for (int mf = 0; mf < 2; ++mf)
#pragma unroll
    for (int r = 0; r < 4; ++r) {
      float inv = 1.0f / lstate[mf][r];
      long qg = qb + (w << 5) + mf * 16 + (g << 2) + r;
      unsigned short* dst = AO + ((long)b * SN + qg) * DN + h * HDN;
#pragma unroll
      for (int nf = 0; nf < 4; ++nf)
        dst[nf * 16 + rl] = f2b(O[mf][nf][r] * inv);
    }
}

extern "C" void kernel_launch(void* const* d_in, const int* in_sizes, int n_in,
                              void* d_out, int out_size, void* d_ws, size_t ws_size,
                              hipStream_t stream) {
  (void)in_sizes; (void)n_in; (void)out_size; (void)ws_size;
  const float* q    = (const float*)d_in[0];
  const float* k    = (const float*)d_in[1];
  const float* v    = (const float*)d_in[2];
  const float* mask = (const float*)d_in[3];
  const float* Wq   = (const float*)d_in[4];
  const float* bq   = (const float*)d_in[5];
  const float* Wk   = (const float*)d_in[6];
  const float* bk   = (const float*)d_in[7];
  const float* Wv   = (const float*)d_in[8];
  const float* bv   = (const float*)d_in[9];
  const float* Wo   = (const float*)d_in[10];
  const float* bo   = (const float*)d_in[11];

  char* ws = (char*)d_ws;
  unsigned short* Xb = (unsigned short*)ws;                                  // 16.78 MB (X / later AO)
  unsigned short* Wt = (unsigned short*)(ws + (size_t)16777216);             // 8.39 MB
  unsigned short* Qh = (unsigned short*)(ws + (size_t)16777216 + 8388608);   // 16.78 MB
  unsigned short* Kh = Qh + (size_t)8192 * 1024;
  unsigned short* Vh = Kh + (size_t)8192 * 1024;  // holds V^T as [B][D][S]

  wtrans<<<dim3(32, 32, 4), dim3(32, 8), 0, stream>>>(Wq, Wk, Wv, Wo, Wt);

  // Q projection
  cvtbf16<<<2048, 256, 0, stream>>>(q, Xb);
  gemm128<0><<<dim3(64, 8), 256, 0, stream>>>(Xb, Wt + (size_t)0 * 1024 * 1024, bq,
                                              Qh, 8192, 1024, 1024);
  // K projection
  cvtbf16<<<2048, 256, 0, stream>>>(k, Xb);
  gemm128<0><<<dim3(64, 8), 256, 0, stream>>>(Xb, Wt + (size_t)1 * 1024 * 1024, bk,
                                              Kh, 8192, 1024, 1024);
  // V projection -> transposed output [B][D][S]
  cvtbf16<<<2048, 256, 0, stream>>>(v, Xb);
  gemm128<2><<<dim3(64, 8), 256, 0, stream>>>(Xb, Wt + (size_t)2 * 1024 * 1024, bv,
                                              Vh, 8192, 1024, 1024);

  attnk<<<dim3(16, 16, 4), 256, 0, stream>>>(Qh, Kh, Vh, mask, Xb);

  gemm128<1><<<dim3(64, 8), 256, 0, stream>>>(Xb, Wt + (size_t)3 * 1024 * 1024, bo,
                                              d_out, 8192, 1024, 1024);
}

// Round 3
// 383.640 us; speedup vs baseline: 1.2878x; 1.2878x over previous
//
#include <hip/hip_runtime.h>

#define DN 1024
#define SN 2048
#define BATCH 4
#define HN 16
#define HDN 64

typedef __attribute__((ext_vector_type(8))) short bf16x8;
typedef __attribute__((ext_vector_type(4))) float f32x4;
typedef __attribute__((ext_vector_type(16))) float f32x16;
typedef __attribute__((ext_vector_type(4))) unsigned int u32x4;

static __device__ __forceinline__ unsigned short f2b(float f) {
  unsigned u = __float_as_uint(f);
  unsigned r = (u + 0x7fffu + ((u >> 16) & 1u)) >> 16;
  return (unsigned short)r;
}

static __device__ __forceinline__ void gload16(const void* g, const void* l) {
  __builtin_amdgcn_global_load_lds(
      (const __attribute__((address_space(1))) unsigned int*)g,
      (__attribute__((address_space(3))) unsigned int*)l, 16, 0, 0);
}

static __device__ __forceinline__ float vmax16(const f32x16& v) {
  float a0 = fmaxf(v[0], v[1]), a1 = fmaxf(v[2], v[3]);
  float a2 = fmaxf(v[4], v[5]), a3 = fmaxf(v[6], v[7]);
  float a4 = fmaxf(v[8], v[9]), a5 = fmaxf(v[10], v[11]);
  float a6 = fmaxf(v[12], v[13]), a7 = fmaxf(v[14], v[15]);
  float b0 = fmaxf(a0, a1), b1 = fmaxf(a2, a3);
  float b2 = fmaxf(a4, a5), b3 = fmaxf(a6, a7);
  return fmaxf(fmaxf(b0, b1), fmaxf(b2, b3));
}

static __device__ __forceinline__ float vsum16(const f32x16& v) {
  float a0 = v[0] + v[1], a1 = v[2] + v[3];
  float a2 = v[4] + v[5], a3 = v[6] + v[7];
  float a4 = v[8] + v[9], a5 = v[10] + v[11];
  float a6 = v[12] + v[13], a7 = v[14] + v[15];
  float b0 = a0 + a1, b1 = a2 + a3, b2 = a4 + a5, b3 = a6 + a7;
  return (b0 + b1) + (b2 + b3);
}

static __device__ __forceinline__ unsigned cvtpk(float lo, float hi) {
  unsigned w;
  asm volatile("v_cvt_pk_bf16_f32 %0, %1, %2" : "=v"(w) : "v"(lo), "v"(hi));
  return w;
}

// ---------------- weight transpose + bf16 convert: Wt[z][n][k] = bf16(W_z[k][n])
__global__ void wtrans(const float* __restrict__ W0, const float* __restrict__ W1,
                       const float* __restrict__ W2, const float* __restrict__ W3,
                       unsigned short* __restrict__ Wt) {
  __shared__ float tile[32][33];
  const int z = blockIdx.z;
  const float* W = (z == 0) ? W0 : (z == 1) ? W1 : (z == 2) ? W2 : W3;
  const int tx = threadIdx.x, ty = threadIdx.y;
  const int n0 = blockIdx.x * 32, k0 = blockIdx.y * 32;
#pragma unroll
  for (int j = ty; j < 32; j += 8)
    tile[j][tx] = W[(long)(k0 + j) * DN + n0 + tx];
  __syncthreads();
  unsigned short* o = Wt + (long)z * DN * DN;
#pragma unroll
  for (int j = ty; j < 32; j += 8)
    o[(long)(n0 + j) * DN + k0 + tx] = f2b(tile[tx][j]);
}

// ---------------- fp32 -> bf16 convert (8192*1024 elems)
__global__ void cvtbf16(const float* __restrict__ x, unsigned short* __restrict__ y) {
  const float4* xv = (const float4*)x;
  ushort4* yv = (ushort4*)y;
  for (int i = blockIdx.x * 256 + threadIdx.x; i < (8192 * 1024 / 4); i += 2048 * 256) {
    float4 vv = xv[i];
    ushort4 o;
    o.x = f2b(vv.x); o.y = f2b(vv.y); o.z = f2b(vv.z); o.w = f2b(vv.w);
    yv[i] = o;
  }
}

// ---------------- bf16 GEMM: C = A[M,K] * Bt[N,K]^T + bias, 128x128 tile, BK=32
// OUTMODE: 0 = bf16 row-major [M][N]; 1 = fp32 row-major [M][N]; 2 = bf16 [B][N][S] (V^T)
template <int OUTMODE>
__global__ __launch_bounds__(256, 2) void gemm128(
    const unsigned short* __restrict__ A, const unsigned short* __restrict__ Bt,
    const float* __restrict__ bias, void* __restrict__ Cout, int M, int N, int K) {
  __shared__ unsigned short Asm[128 * 32];
  __shared__ unsigned short Bsm[128 * 32];
  const int t = threadIdx.x;
  const int lane = t & 63, w = t >> 6;
  const int rl = lane & 15, g = lane >> 4;
  const int wm = (w >> 1) << 6, wn = (w & 1) << 6;
  const long bm = (long)blockIdx.x * 128, bn = (long)blockIdx.y * 128;

  f32x4 acc[4][4] = {};

  const int c0 = t, c1 = 256 + t;
  const int r0 = c0 >> 2, s0 = c0 & 3;
  const int r1 = c1 >> 2, s1 = c1 & 3;

  for (int k0 = 0; k0 < K; k0 += 32) {
    __syncthreads();
    gload16(A + (bm + r0) * K + k0 + s0 * 8, Asm + (w << 6) * 8);
    gload16(A + (bm + r1) * K + k0 + s1 * 8, Asm + (256 + (w << 6)) * 8);
    gload16(Bt + (bn + r0) * K + k0 + s0 * 8, Bsm + (w << 6) * 8);
    gload16(Bt + (bn + r1) * K + k0 + s1 * 8, Bsm + (256 + (w << 6)) * 8);
    asm volatile("s_waitcnt vmcnt(0)" ::: "memory");
    __syncthreads();
    bf16x8 af[4], bfr[4];
#pragma unroll
    for (int mf = 0; mf < 4; ++mf)
      af[mf] = *(const bf16x8*)(Asm + (wm + mf * 16 + rl) * 32 + g * 8);
#pragma unroll
    for (int nf = 0; nf < 4; ++nf)
      bfr[nf] = *(const bf16x8*)(Bsm + (wn + nf * 16 + rl) * 32 + g * 8);
#pragma unroll
    for (int mf = 0; mf < 4; ++mf)
#pragma unroll
      for (int nf = 0; nf < 4; ++nf)
        acc[mf][nf] = __builtin_amdgcn_mfma_f32_16x16x32_bf16(af[mf], bfr[nf], acc[mf][nf], 0, 0, 0);
  }

#pragma unroll
  for (int mf = 0; mf < 4; ++mf)
#pragma unroll
    for (int nf = 0; nf < 4; ++nf) {
      long col = bn + wn + nf * 16 + rl;
      float bv = bias[col];
      if (OUTMODE == 2) {
        long row0 = bm + wm + mf * 16 + g * 4;
        long bb = row0 >> 11, ss = row0 & 2047;
        ushort4 pack;
        pack.x = f2b(acc[mf][nf][0] + bv);
        pack.y = f2b(acc[mf][nf][1] + bv);
        pack.z = f2b(acc[mf][nf][2] + bv);
        pack.w = f2b(acc[mf][nf][3] + bv);
        *(ushort4*)((unsigned short*)Cout + (bb * DN + col) * SN + ss) = pack;
      } else {
#pragma unroll
        for (int r = 0; r < 4; ++r) {
          long row = bm + wm + mf * 16 + g * 4 + r;
          float vv = acc[mf][nf][r] + bv;
          if (OUTMODE == 1)
            ((float*)Cout)[row * N + col] = vv;
          else
            ((unsigned short*)Cout)[row * N + col] = f2b(vv);
        }
      }
    }
}

// ---------------- flash attention, swapped-operand 32x32x16 structure
// grid (S/128, H, B), 256 thr = 4 waves x 32 q-rows. Each lane owns ONE q-row.
// S^T = mfma(K, Q): lane q = lane&31; P fully in-register via cvt_pk + permlane32_swap.
// Qh/Kh: [B][S][D] bf16; Vt: [B][D][S] bf16; AO: [B][S][D] bf16
__global__ __launch_bounds__(256, 4) void attnk(
    const unsigned short* __restrict__ Qh, const unsigned short* __restrict__ Kh,
    const unsigned short* __restrict__ Vt, const float* __restrict__ mask,
    unsigned short* __restrict__ AO) {
  const int t = threadIdx.x, lane = t & 63, w = t >> 6;
  const int ql = lane & 31, hi = lane >> 5;
  const int qb = blockIdx.x * 128;
  const int h = blockIdx.y, b = blockIdx.z;

  __shared__ unsigned short KV[2][8192];  // per buf: K[64][64] swz @0, V^T[64][64] swz @4096
  __shared__ float ms[SN];                // mask * -1e9

  const unsigned short* Kp = Kh + (long)b * SN * DN + h * HDN;
  const unsigned short* Vp = Vt + ((long)b * DN + h * HDN) * SN;

  {  // mask -> LDS, pre-multiplied by -1e9
    const float4* mp = (const float4*)(mask + (long)b * SN);
    float4* md = (float4*)ms;
    float4 v0 = mp[t], v1 = mp[256 + t];
    v0.x *= -1e9f; v0.y *= -1e9f; v0.z *= -1e9f; v0.w *= -1e9f;
    v1.x *= -1e9f; v1.y *= -1e9f; v1.z *= -1e9f; v1.w *= -1e9f;
    md[t] = v0;
    md[256 + t] = v1;
  }

  // Q B-frags direct from global: qf[f] = Q[q][f*16 + hi*8 .. +7]
  const unsigned short* Qp = Qh + ((long)b * SN + qb + (w << 5) + ql) * DN + h * HDN;
  bf16x8 qf[4];
#pragma unroll
  for (int f = 0; f < 4; ++f)
    qf[f] = *(const bf16x8*)(Qp + f * 16 + hi * 8);

#define STAGE(buf, tt)                                                          \
  {                                                                             \
    const int base_ = (tt) * 64;                                                \
    _Pragma("unroll") for (int i_ = 0; i_ < 2; ++i_) {                          \
      int c_ = i_ * 256 + t;                                                    \
      int r_ = c_ >> 3, sl_ = c_ & 7;                                           \
      gload16(Kp + (long)(base_ + r_) * DN + ((sl_ ^ (r_ & 7)) << 3),           \
              &KV[buf][(i_ * 256 + (w << 6)) * 8]);                             \
      gload16(Vp + (long)r_ * SN + base_ + ((sl_ ^ (r_ & 7)) << 3),             \
              &KV[buf][4096 + (i_ * 256 + (w << 6)) * 8]);                      \
    }                                                                           \
  }

  STAGE(0, 0);
  asm volatile("s_waitcnt vmcnt(0)" ::: "memory");
  __syncthreads();

  f32x16 O[2] = {};   // O^T accs: da=0,1 (d rows da*32+..)
  float m_run = -1e30f, l_run = 0.f;
  const float ISC = 0.015625f;  // 1/64

  for (int tt = 0; tt < SN / 64; ++tt) {
    const int cur = tt & 1;
    if (tt < SN / 64 - 1) STAGE(cur ^ 1, tt + 1);
    const unsigned short* Kb = &KV[cur][0];
    const unsigned short* Vb = &KV[cur][4096];

    // ---- QK^T: S^T[k][q], two 32-k accs
    f32x16 s[2] = {};
#pragma unroll
    for (int f = 0; f < 4; ++f) {
      const int kr0 = ql, kr1 = 32 + ql;
      bf16x8 a0 = *(const bf16x8*)(Kb + kr0 * 64 + (((f * 2 + hi) ^ (kr0 & 7)) << 3));
      bf16x8 a1 = *(const bf16x8*)(Kb + kr1 * 64 + (((f * 2 + hi) ^ (kr1 & 7)) << 3));
      s[0] = __builtin_amdgcn_mfma_f32_32x32x16_bf16(a0, qf[f], s[0], 0, 0, 0);
      s[1] = __builtin_amdgcn_mfma_f32_32x32x16_bf16(a1, qf[f], s[1], 0, 0, 0);
    }

    // ---- scale + mask (reg r -> k = kb*32 + 8*(r>>2) + 4*hi + (r&3))
#pragma unroll
    for (int j = 0; j < 4; ++j) {
      f32x4 m0 = *(const f32x4*)(ms + tt * 64 + 8 * j + 4 * hi);
      f32x4 m1 = *(const f32x4*)(ms + tt * 64 + 32 + 8 * j + 4 * hi);
#pragma unroll
      for (int i2 = 0; i2 < 4; ++i2) {
        s[0][4 * j + i2] = fmaf(s[0][4 * j + i2], ISC, m0[i2]);
        s[1][4 * j + i2] = fmaf(s[1][4 * j + i2], ISC, m1[i2]);
      }
    }

    // ---- online softmax, lane-local row (defer-max THR=8)
    float pm = fmaxf(vmax16(s[0]), vmax16(s[1]));
    pm = fmaxf(pm, __shfl_xor(pm, 32));
    if (__any(pm - m_run > 8.f)) {
      float mn = fmaxf(m_run, pm);
      float co = __expf(m_run - mn);
      m_run = mn;
      l_run *= co;
#pragma unroll
      for (int r = 0; r < 16; ++r) { O[0][r] *= co; O[1][r] *= co; }
    }
#pragma unroll
    for (int r = 0; r < 16; ++r) {
      s[0][r] = __expf(s[0][r] - m_run);
      s[1][r] = __expf(s[1][r] - m_run);
    }
    float rs = vsum16(s[0]) + vsum16(s[1]);
    rs += __shfl_xor(rs, 32);
    l_run += rs;

    // ---- P -> bf16 words: aw[j]=k{8j+4hi+0,1}, bw[j]=k{8j+4hi+2,3} (j global 0..7)
    unsigned aw[8], bw[8];
#pragma unroll
    for (int j = 0; j < 4; ++j) {
      aw[j]     = cvtpk(s[0][4 * j], s[0][4 * j + 1]);
      bw[j]     = cvtpk(s[0][4 * j + 2], s[0][4 * j + 3]);
      aw[4 + j] = cvtpk(s[1][4 * j], s[1][4 * j + 1]);
      bw[4 + j] = cvtpk(s[1][4 * j + 2], s[1][4 * j + 3]);
    }
    // ---- permlane32_swap -> B-frags pb[ks]: k = ks*16 + hi*8 + {0..7}
    bf16x8 pb[4];
#pragma unroll
    for (int ks = 0; ks < 4; ++ks) {
      unsigned x0 = aw[2 * ks], y0 = aw[2 * ks + 1];
      unsigned x1 = bw[2 * ks], y1 = bw[2 * ks + 1];
      asm volatile("v_permlane32_swap_b32 %0, %1" : "+v"(x0), "+v"(y0));
      asm volatile("v_permlane32_swap_b32 %0, %1" : "+v"(x1), "+v"(y1));
      u32x4 wv = {x0, x1, y0, y1};  // c0,c1,c2,c3
      pb[ks] = __builtin_bit_cast(bf16x8, wv);
    }

    // ---- PV: O^T += V^T * P^T
#pragma unroll
    for (int da = 0; da < 2; ++da) {
      const int dr = da * 32 + ql;
#pragma unroll
      for (int ks = 0; ks < 4; ++ks) {
        bf16x8 va = *(const bf16x8*)(Vb + dr * 64 + (((ks * 2 + hi) ^ (dr & 7)) << 3));
        O[da] = __builtin_amdgcn_mfma_f32_32x32x16_bf16(va, pb[ks], O[da], 0, 0, 0);
      }
    }

    asm volatile("s_waitcnt vmcnt(0)" ::: "memory");
    __syncthreads();
  }
#undef STAGE

  // ---- epilogue: O^T[d][q] / l -> AO[b][q][h*64+d]
  float inv = 1.0f / l_run;
  unsigned short* dst = AO + ((long)b * SN + qb + (w << 5) + ql) * DN + h * HDN;
#pragma unroll
  for (int da = 0; da < 2; ++da)
#pragma unroll
    for (int j = 0; j < 4; ++j) {
      ushort4 pk;
      pk.x = f2b(O[da][4 * j + 0] * inv);
      pk.y = f2b(O[da][4 * j + 1] * inv);
      pk.z = f2b(O[da][4 * j + 2] * inv);
      pk.w = f2b(O[da][4 * j + 3] * inv);
      *(ushort4*)(dst + da * 32 + 8 * j + 4 * hi) = pk;
    }
}

extern "C" void kernel_launch(void* const* d_in, const int* in_sizes, int n_in,
                              void* d_out, int out_size, void* d_ws, size_t ws_size,
                              hipStream_t stream) {
  (void)in_sizes; (void)n_in; (void)out_size; (void)ws_size;
  const float* q    = (const float*)d_in[0];
  const float* k    = (const float*)d_in[1];
  const float* v    = (const float*)d_in[2];
  const float* mask = (const float*)d_in[3];
  const float* Wq   = (const float*)d_in[4];
  const float* bq   = (const float*)d_in[5];
  const float* Wk   = (const float*)d_in[6];
  const float* bk   = (const float*)d_in[7];
  const float* Wv   = (const float*)d_in[8];
  const float* bv   = (const float*)d_in[9];
  const float* Wo   = (const float*)d_in[10];
  const float* bo   = (const float*)d_in[11];

  char* ws = (char*)d_ws;
  unsigned short* Xb = (unsigned short*)ws;                                  // 16.78 MB (X / later AO)
  unsigned short* Wt = (unsigned short*)(ws + (size_t)16777216);             // 8.39 MB
  unsigned short* Qh = (unsigned short*)(ws + (size_t)16777216 + 8388608);   // 16.78 MB
  unsigned short* Kh = Qh + (size_t)8192 * 1024;
  unsigned short* Vh = Kh + (size_t)8192 * 1024;  // holds V^T as [B][D][S]

  wtrans<<<dim3(32, 32, 4), dim3(32, 8), 0, stream>>>(Wq, Wk, Wv, Wo, Wt);

  cvtbf16<<<2048, 256, 0, stream>>>(q, Xb);
  gemm128<0><<<dim3(64, 8), 256, 0, stream>>>(Xb, Wt + (size_t)0 * 1024 * 1024, bq,
                                              Qh, 8192, 1024, 1024);
  cvtbf16<<<2048, 256, 0, stream>>>(k, Xb);
  gemm128<0><<<dim3(64, 8), 256, 0, stream>>>(Xb, Wt + (size_t)1 * 1024 * 1024, bk,
                                              Kh, 8192, 1024, 1024);
  cvtbf16<<<2048, 256, 0, stream>>>(v, Xb);
  gemm128<2><<<dim3(64, 8), 256, 0, stream>>>(Xb, Wt + (size_t)2 * 1024 * 1024, bv,
                                              Vh, 8192, 1024, 1024);

  attnk<<<dim3(16, 16, 4), 256, 0, stream>>>(Qh, Kh, Vh, mask, Xb);

  gemm128<1><<<dim3(64, 8), 256, 0, stream>>>(Xb, Wt + (size_t)3 * 1024 * 1024, bo,
                                              d_out, 8192, 1024, 1024);
}